// Round 1
// 466.986 us; speedup vs baseline: 1.0242x; 1.0242x over previous
//
#include <hip/hip_runtime.h>
#include <stdint.h>

typedef unsigned short ushort_t;
typedef __attribute__((ext_vector_type(8))) __bf16 bf16x8;
typedef __attribute__((ext_vector_type(4))) float f32x4;
typedef __attribute__((ext_vector_type(16))) float f32x16;

#define MFMA16(a, b, c) __builtin_amdgcn_mfma_f32_16x16x32_bf16((a), (b), (c), 0, 0, 0)
#define MFMA32(a, b, c) __builtin_amdgcn_mfma_f32_32x32x16_bf16((a), (b), (c), 0, 0, 0)

#define STR_(x) #x
#define STR(x) STR_(x)

__device__ __forceinline__ ushort_t f2bf(float f) {
    unsigned u = __float_as_uint(f);
    u += 0x7fffu + ((u >> 16) & 1u);   // round-to-nearest-even
    return (ushort_t)(u >> 16);
}

// async global->LDS 16B (m97 path). LDS dest must be wave-uniform base + lane*16.
typedef __attribute__((address_space(1))) const unsigned char g_u8;
typedef __attribute__((address_space(3))) unsigned char l_u8;
__device__ __forceinline__ void gload16(const void* g, void* l) {
    __builtin_amdgcn_global_load_lds((g_u8*)g, (l_u8*)(unsigned int)(uintptr_t)l, 16, 0, 0);
}

// ---------------------------------------------------------------- fused casts f32 -> bf16
__global__ __launch_bounds__(256) void cast_multi(const float* __restrict__ x,
                                                  const float* __restrict__ wq,
                                                  const float* __restrict__ wk,
                                                  const float* __restrict__ wv,
                                                  ushort_t* __restrict__ xb,
                                                  ushort_t* __restrict__ wqb,
                                                  ushort_t* __restrict__ wkb,
                                                  ushort_t* __restrict__ wvb) {
    int i = blockIdx.x * 256 + threadIdx.x;
    const float* in; ushort_t* out; int off;
    if (i < 2097152)      { in = x;  out = xb;  off = i; }
    else if (i < 6291456) { in = wq; out = wqb; off = i - 2097152; }
    else if (i < 7340032) { in = wk; out = wkb; off = i - 6291456; }
    else                  { in = wv; out = wvb; off = i - 7340032; }
    float4 v = ((const float4*)in)[off];
    ushort4 o;
    o.x = f2bf(v.x); o.y = f2bf(v.y); o.z = f2bf(v.z); o.w = f2bf(v.w);
    ((ushort4*)out)[off] = o;
}

__global__ __launch_bounds__(256) void cast_f32_bf16(const float* __restrict__ in,
                                                     ushort_t* __restrict__ out, int n4) {
    int i = blockIdx.x * 256 + threadIdx.x;
    if (i < n4) {
        float4 v = ((const float4*)in)[i];
        ushort4 o;
        o.x = f2bf(v.x); o.y = f2bf(v.y); o.z = f2bf(v.z); o.w = f2bf(v.w);
        ((ushort4*)out)[i] = o;
    }
}

// ---------------------------------------------------------------- 8-phase counted-vmcnt K-loop
// Geometry: BM=256 rows of A staged as [2] dbuf; BROWS rows of B staged as [3] tribuf.
// BK=64. 512 threads, 8 waves. Swizzle: 16B chunk (row,kc) lives at slot row*8 + (kc^(row&7));
// staged linearly via pre-swizzled global source (slot s: row=s>>3, kc=(s&7)^(row&7)), so
// per-thread: srow=tid>>3, skc=(tid&7)^(srow&7) is the SAME for every 64-row group p.
// Pipeline: A staged 1 tile ahead (dbuf), B staged 2 tiles ahead (tribuf). Per K-tile
// iter t: phases ks=0..3, each {ds_read frags | issue 2(or 1) stage loads | s_barrier |
// lgkmcnt(0) | setprio(1) MFMA cluster setprio(0) | s_barrier}. Issue order per iter:
// A(t+1) x ALOADS (ks0,ks1), B(t+2) x BLOADS (ks2,ks3). End-of-iter wait = vmcnt(BLOADS):
// drains A(t+1)+B(t+1), leaves B(t+2) in flight — never vmcnt(0) in steady state (T4).
// Region safety: A[(t+1)&1] / B[(t+2)%3] last read in iter t-1, whose ds_reads retired
// before its final barrier; stage issues are after that barrier. Requires NT >= 2.
#define GEMM_K_LOOP_8P(Aarr, Barr, KDIM, AI, BJ, ALOADS, BLOADS, VM)                     \
    const int l32 = lane & 31, hi = lane >> 5, r7 = l32 & 7;                             \
    const int srow = tid >> 3;                                                           \
    const int skc = (tid & 7) ^ (srow & 7);                                              \
    const ushort_t* aS = (Aarr) + (size_t)(bm + srow) * (KDIM) + skc * 8;                \
    const ushort_t* bS = (Barr) + (size_t)(bn + srow) * (KDIM) + skc * 8;                \
    const int lofs = tid * 8;                                                            \
    const int NT = (KDIM) >> 6;                                                          \
    _Pragma("unroll")                                                                    \
    for (int p = 0; p < (ALOADS); p++)                                                   \
        gload16(aS + (size_t)p * 64 * (KDIM), &Asl[0][lofs + p * 4096]);                 \
    _Pragma("unroll")                                                                    \
    for (int p = 0; p < (BLOADS); p++)                                                   \
        gload16(bS + (size_t)p * 64 * (KDIM), &Bsl[0][lofs + p * 4096]);                 \
    _Pragma("unroll")                                                                    \
    for (int p = 0; p < (BLOADS); p++)                                                   \
        gload16(bS + (size_t)p * 64 * (KDIM) + 64, &Bsl[1][lofs + p * 4096]);            \
    asm volatile("s_waitcnt vmcnt(" STR(VM) ")" ::: "memory");                           \
    __builtin_amdgcn_s_barrier();                                                        \
    asm volatile("" ::: "memory");                                                       \
    int cbB = 0, sbB = 2;                                                                \
    for (int t = 0; t < NT; t++) {                                                       \
        const int cbA = t & 1;                                                           \
        const ushort_t* Ab = Asl[cbA];                                                   \
        const ushort_t* Bb = Bsl[cbB];                                                   \
        ushort_t* AbS = Asl[cbA ^ 1];                                                    \
        ushort_t* BbS = Bsl[sbB];                                                        \
        const bool stA = (t + 1 < NT);                                                   \
        const bool stB = (t + 2 < NT);                                                   \
        const size_t koA = (size_t)(t + 1) * 64;                                         \
        const size_t koB = (size_t)(t + 2) * 64;                                         \
        _Pragma("unroll")                                                                \
        for (int ks = 0; ks < 4; ks++) {                                                 \
            const int swz = ((ks * 2 + hi) ^ r7) << 3;                                   \
            bf16x8 af[AI], bfr[BJ];                                                      \
            _Pragma("unroll")                                                            \
            for (int i = 0; i < (AI); i++)                                               \
                af[i] = *(const bf16x8*)(&Ab[(wm + i * 32 + l32) * 64 + swz]);           \
            _Pragma("unroll")                                                            \
            for (int j = 0; j < (BJ); j++)                                               \
                bfr[j] = *(const bf16x8*)(&Bb[(wn + j * 32 + l32) * 64 + swz]);          \
            if (ks == 0 && stA) {                                                        \
                _Pragma("unroll")                                                        \
                for (int p = 0; p < (ALOADS) / 2; p++)                                   \
                    gload16(aS + koA + (size_t)p * 64 * (KDIM), &AbS[lofs + p * 4096]);  \
            }                                                                            \
            if (ks == 1 && stA) {                                                        \
                _Pragma("unroll")                                                        \
                for (int p = (ALOADS) / 2; p < (ALOADS); p++)                            \
                    gload16(aS + koA + (size_t)p * 64 * (KDIM), &AbS[lofs + p * 4096]);  \
            }                                                                            \
            if (ks == 2 && stB) {                                                        \
                _Pragma("unroll")                                                        \
                for (int p = 0; p < (BLOADS) / 2; p++)                                   \
                    gload16(bS + koB + (size_t)p * 64 * (KDIM), &BbS[lofs + p * 4096]);  \
            }                                                                            \
            if (ks == 3 && stB) {                                                        \
                _Pragma("unroll")                                                        \
                for (int p = (BLOADS) / 2; p < (BLOADS); p++)                            \
                    gload16(bS + koB + (size_t)p * 64 * (KDIM), &BbS[lofs + p * 4096]);  \
            }                                                                            \
            __builtin_amdgcn_s_barrier();                                                \
            asm volatile("s_waitcnt lgkmcnt(0)" ::: "memory");                           \
            __builtin_amdgcn_sched_barrier(0);                                           \
            __builtin_amdgcn_s_setprio(1);                                               \
            _Pragma("unroll")                                                            \
            for (int i = 0; i < (AI); i++) {                                             \
                _Pragma("unroll")                                                        \
                for (int j = 0; j < (BJ); j++)                                           \
                    acc[i][j] = MFMA32(af[i], bfr[j], acc[i][j]);                        \
            }                                                                            \
            __builtin_amdgcn_s_setprio(0);                                               \
            if (ks < 3) {                                                                \
                __builtin_amdgcn_s_barrier();                                            \
            } else {                                                                     \
                if (stB) { asm volatile("s_waitcnt vmcnt(" STR(VM) ")" ::: "memory"); }  \
                else     { asm volatile("s_waitcnt vmcnt(0)" ::: "memory"); }            \
                __builtin_amdgcn_s_barrier();                                            \
                asm volatile("" ::: "memory");                                           \
                __builtin_amdgcn_sched_barrier(0);                                       \
            }                                                                            \
        }                                                                                \
        if (++cbB == 3) cbB = 0;                                                         \
        if (++sbB == 3) sbB = 0;                                                         \
    }

// ---------------------------------------------------------------- fused QKV GEMM (+ wo cast tail)
// BM=256 x BN=256, wave tile 128x64 (acc 4x2), grid (8, 24 [+64 cast tail]).
// by<16: Q (+rope,*scale); by<20: K (+rope); by<24: V transposed; by>=24: wo cast.
__global__ __launch_bounds__(512, 2) void gemm_qkv(const ushort_t* __restrict__ A,
                                                   const ushort_t* __restrict__ Wq,
                                                   const ushort_t* __restrict__ Wk,
                                                   const ushort_t* __restrict__ Wv,
                                                   ushort_t* __restrict__ Qo,
                                                   ushort_t* __restrict__ Ko,
                                                   ushort_t* __restrict__ VtO,
                                                   const float* __restrict__ cosp,
                                                   const float* __restrict__ sinp,
                                                   const float* __restrict__ wo,
                                                   ushort_t* __restrict__ wob) {
    const int by = blockIdx.y;
    const int tid = threadIdx.x;

    if (by >= 24) {   // wo cast tail: 512 blocks x (512 threads x 16 float4)
        const int ci = (by - 24) * gridDim.x + blockIdx.x;   // 0..511
        const float4* src = (const float4*)wo;
        ushort4* dst = (ushort4*)wob;
        int base = ci * 8192 + tid;
#pragma unroll
        for (int p = 0; p < 16; p++) {
            float4 v = src[base + p * 512];
            ushort4 o;
            o.x = f2bf(v.x); o.y = f2bf(v.y); o.z = f2bf(v.z); o.w = f2bf(v.w);
            dst[base + p * 512] = o;
        }
        return;
    }

    const ushort_t* B;
    int region, bn;
    if (by < 16)      { region = 0; B = Wq; bn = by * 256; }
    else if (by < 20) { region = 1; B = Wk; bn = (by - 16) * 256; }
    else              { region = 2; B = Wv; bn = (by - 20) * 256; }
    const int bm = blockIdx.x * 256;

    __shared__ __align__(16) ushort_t Asl[2][256 * 64];   //  64 KiB
    __shared__ __align__(16) ushort_t Bsl[3][256 * 64];   //  96 KiB (total 160 KiB)
    const int w = tid >> 6, lane = tid & 63;
    const int wm = (w >> 2) * 128, wn = (w & 3) * 64;     // waves 2M x 4N
    f32x16 acc[4][2] = {};

    GEMM_K_LOOP_8P(A, B, 4096, 4, 2, 4, 4, 4)

    // D layout: col = lane&31, row = (reg&3) + 8*(reg>>2) + 4*(lane>>5)  [m74/m101]
    const float qscale = 0.08838834764831845f;  // 1/sqrt(128)
    if (region < 2) {
        ushort_t* C = (region == 0) ? Qo : Ko;
        const int Nc = (region == 0) ? 4096 : 1024;
        const float scl = (region == 0) ? qscale : 1.0f;
#pragma unroll
        for (int i = 0; i < 4; i++)
#pragma unroll
            for (int j = 0; j < 2; j++) {
                const int col = bn + wn + j * 32 + l32;
                const int pj = (col & 127) >> 1;
#pragma unroll
                for (int r = 0; r < 16; r++) {
                    const int row = bm + wm + i * 32 + (r & 3) + 8 * (r >> 2) + 4 * hi;
                    float v = acc[i][j][r];
                    float p = __shfl_xor(v, 1);     // partner column (col^1)
                    float c = cosp[row * 64 + pj], s = sinp[row * 64 + pj];
                    float res = (col & 1) ? fmaf(p, s, v * c)   // odd: x1*s + x2*c
                                          : (v * c - p * s);    // even: x1*c - x2*s
                    C[(size_t)row * Nc + col] = f2bf(res * scl);
                }
            }
    } else {
        // V^T: VtO[dim][token]; regs g*4..g*4+3 are 4 consecutive tokens -> 8B packed store
#pragma unroll
        for (int i = 0; i < 4; i++)
#pragma unroll
            for (int j = 0; j < 2; j++) {
                const int col = bn + wn + j * 32 + l32;   // dim 0..1023
#pragma unroll
                for (int g = 0; g < 4; g++) {
                    const int rowb = bm + wm + i * 32 + g * 8 + 4 * hi;  // token base
                    ushort4 pk;
                    pk.x = f2bf(acc[i][j][g * 4 + 0]);
                    pk.y = f2bf(acc[i][j][g * 4 + 1]);
                    pk.z = f2bf(acc[i][j][g * 4 + 2]);
                    pk.w = f2bf(acc[i][j][g * 4 + 3]);
                    *(ushort4*)(VtO + (size_t)col * 2048 + rowb) = pk;
                }
            }
    }
}

// ---------------------------------------------------------------- GEMM: C = A @ B^T (wo, fp32 out)
// BM=256 x BN=128, wave tile 64x64 (waves 4M x 2N), grid (8,32) = 256 blocks = 1/CU.
__global__ __launch_bounds__(512, 2) void gemm_bt(const ushort_t* __restrict__ A,
                                                  const ushort_t* __restrict__ B,
                                                  float* __restrict__ C,
                                                  int M, int N, int K) {
    const int bm = blockIdx.x * 256, bn = blockIdx.y * 128;
    __shared__ __align__(16) ushort_t Asl[2][256 * 64];   // 64 KiB
    __shared__ __align__(16) ushort_t Bsl[3][128 * 64];   // 48 KiB
    const int tid = threadIdx.x;
    const int w = tid >> 6, lane = tid & 63;
    const int wm = (w >> 1) * 64, wn = (w & 1) * 64;      // waves 4M x 2N
    f32x16 acc[2][2] = {};

    GEMM_K_LOOP_8P(A, B, K, 2, 2, 4, 2, 2)

#pragma unroll
    for (int i = 0; i < 2; i++)
#pragma unroll
        for (int j = 0; j < 2; j++) {
            const int col = bn + wn + j * 32 + l32;
#pragma unroll
            for (int r = 0; r < 16; r++) {
                const int row = bm + wm + i * 32 + (r & 3) + 8 * (r >> 2) + 4 * hi;
                C[(size_t)row * N + col] = acc[i][j][r];
            }
        }
}

// ---------------------------------------------------------------- flash attention
// grid (16, 32), 256 threads, 1 head/block => 512 blocks = 2/CU (co-scheduling).
// Block handles q-tiles qt=bx and 31-bx (uniform 33 iters). Wave w owns rows w*16..w*16+15.
__global__ __launch_bounds__(256) void flash_attn(const ushort_t* __restrict__ Q,
                                                  const ushort_t* __restrict__ Kp,
                                                  const ushort_t* __restrict__ Vt,
                                                  ushort_t* __restrict__ Y) {
    const int h = blockIdx.y, kh = h >> 2;
    const int tid = threadIdx.x;
    const int w = tid >> 6, lane = tid & 63;
    const int quad = lane >> 4, l16 = lane & 15;

    __shared__ __align__(16) ushort_t Ks[64 * 136];    // keys x dims
    __shared__ __align__(16) ushort_t VtS[128 * 88];   // dims x keys (2-way banks)
    __shared__ __align__(16) ushort_t Ps[4 * 16 * 88]; // per-wave P round-trip

    bf16x8 ones;
#pragma unroll
    for (int e = 0; e < 8; e++) ((ushort_t*)&ones)[e] = 0x3F80;  // bf16 1.0

#pragma unroll 1
    for (int phase = 0; phase < 2; phase++) {
        const int qt = (phase == 0) ? blockIdx.x : 31 - blockIdx.x;

        bf16x8 qf[4];
        {
            const ushort_t* qrow = Q + (size_t)(qt * 64 + w * 16 + l16) * 4096 + h * 128 + quad * 8;
#pragma unroll
            for (int ks = 0; ks < 4; ks++) qf[ks] = *(const bf16x8*)(qrow + ks * 32);
        }

        f32x4 o[8] = {};
        f32x4 lacc = {};
        float m_i[4];
#pragma unroll
        for (int r = 0; r < 4; r++) m_i[r] = -1e30f;

        const int ntiles = qt + 1;
        for (int j = 0; j < ntiles; j++) {
            const int t0 = j * 64;
            {   // K tile: 64x128 = 1024 16B-chunks over 256 threads
#pragma unroll
                for (int p = 0; p < 4; p++) {
                    int ck = p * 256 + tid;
                    int r = ck >> 4, c = (ck & 15) * 8;
                    uint4 d = *(const uint4*)(Kp + (size_t)(t0 + r) * 1024 + kh * 128 + c);
                    *(uint4*)(&Ks[r * 136 + c]) = d;
                }
            }
            {   // V^T tile: 128x64 = 1024 chunks
#pragma unroll
                for (int p = 0; p < 4; p++) {
                    int ck = p * 256 + tid;
                    int d = ck >> 3, c = (ck & 7) * 8;
                    uint4 v = *(const uint4*)(Vt + (size_t)(kh * 128 + d) * 2048 + t0 + c);
                    *(uint4*)(&VtS[d * 88 + c]) = v;
                }
            }
            __syncthreads();

            // S = Q @ K^T
            f32x4 s[4] = {};
#pragma unroll
            for (int ct = 0; ct < 4; ct++)
#pragma unroll
                for (int ks = 0; ks < 4; ks++) {
                    bf16x8 kf = *(const bf16x8*)(&Ks[(ct * 16 + l16) * 136 + ks * 32 + quad * 8]);
                    s[ct] = MFMA16(qf[ks], kf, s[ct]);
                }

            if (j == qt) {   // diagonal: causal mask
#pragma unroll
                for (int ct = 0; ct < 4; ct++)
#pragma unroll
                    for (int r = 0; r < 4; r++) {
                        int rg = w * 16 + quad * 4 + r;
                        int cg = ct * 16 + l16;
                        if (cg > rg) s[ct][r] = -1e30f;
                    }
            }

            // online softmax (quad's 16 lanes share rows quad*4+r)
            float alpha[4];
#pragma unroll
            for (int r = 0; r < 4; r++) {
                float v = fmaxf(fmaxf(s[0][r], s[1][r]), fmaxf(s[2][r], s[3][r]));
                v = fmaxf(v, __shfl_xor(v, 1));
                v = fmaxf(v, __shfl_xor(v, 2));
                v = fmaxf(v, __shfl_xor(v, 4));
                v = fmaxf(v, __shfl_xor(v, 8));
                float mn = fmaxf(m_i[r], v);
                alpha[r] = __expf(m_i[r] - mn);
                m_i[r] = mn;
            }
#pragma unroll
            for (int ct = 0; ct < 4; ct++)
#pragma unroll
                for (int r = 0; r < 4; r++)
                    s[ct][r] = __expf(s[ct][r] - m_i[r]);
#pragma unroll
            for (int n = 0; n < 8; n++)
#pragma unroll
                for (int r = 0; r < 4; r++) o[n][r] *= alpha[r];
#pragma unroll
            for (int r = 0; r < 4; r++) lacc[r] *= alpha[r];

            // P: D-layout -> A-layout via per-wave LDS region (wave-private: no barrier)
#pragma unroll
            for (int ct = 0; ct < 4; ct++)
#pragma unroll
                for (int r = 0; r < 4; r++)
                    Ps[w * 1408 + (quad * 4 + r) * 88 + ct * 16 + l16] = f2bf(s[ct][r]);
            __threadfence_block();

            // O += P (16x64) @ V (64x128); row-sum l += P @ 1 via MFMA
#pragma unroll
            for (int ks2 = 0; ks2 < 2; ks2++) {
                bf16x8 pf = *(const bf16x8*)(&Ps[w * 1408 + l16 * 88 + ks2 * 32 + quad * 8]);
                lacc = MFMA16(pf, ones, lacc);
#pragma unroll
                for (int n = 0; n < 8; n++) {
                    bf16x8 vf = *(const bf16x8*)(&VtS[(n * 16 + l16) * 88 + ks2 * 32 + quad * 8]);
                    o[n] = MFMA16(pf, vf, o[n]);
                }
            }
            __syncthreads();
        }

        float inv[4];
#pragma unroll
        for (int r = 0; r < 4; r++) inv[r] = 1.0f / lacc[r];
#pragma unroll
        for (int n = 0; n < 8; n++)
#pragma unroll
            for (int r = 0; r < 4; r++) {
                int row = qt * 64 + w * 16 + quad * 4 + r;
                int col = h * 128 + n * 16 + l16;
                Y[(size_t)row * 4096 + col] = f2bf(o[n][r] * inv[r]);
            }
    }
}

// ---------------------------------------------------------------- launch
extern "C" void kernel_launch(void* const* d_in, const int* in_sizes, int n_in,
                              void* d_out, int out_size, void* d_ws, size_t ws_size,
                              hipStream_t stream) {
    const float* x    = (const float*)d_in[0];
    const float* cosp = (const float*)d_in[1];
    const float* sinp = (const float*)d_in[2];
    const float* wq   = (const float*)d_in[3];
    const float* wk   = (const float*)d_in[4];
    const float* wv   = (const float*)d_in[5];
    const float* wo   = (const float*)d_in[6];
    float* out = (float*)d_out;

    // workspace (bf16 elems)
    ushort_t* xb   = (ushort_t*)d_ws;
    ushort_t* qb   = xb  + (size_t)2048 * 4096;
    ushort_t* yb   = qb  + (size_t)2048 * 4096;
    ushort_t* kb   = yb  + (size_t)2048 * 4096;
    ushort_t* vtb  = kb  + (size_t)2048 * 1024;   // V^T (1024 x 2048)
    ushort_t* wkb  = vtb + (size_t)1024 * 2048;
    ushort_t* wvb  = wkb + (size_t)1024 * 4096;
    ushort_t* wbig = wvb + (size_t)1024 * 4096;   // wq (and wo if !fuse_wo)
    ushort_t* wob  = wbig + (size_t)4096 * 4096;  // separate wo buffer (fused path)
    const size_t need_fused = (size_t)(wob + (size_t)4096 * 4096 - xb) * sizeof(ushort_t);
    const bool fuse_wo = ws_size >= need_fused;

    // 1) input casts (x, wq, wk, wv)
    cast_multi<<<32768, 256, 0, stream>>>(x, wq, wk, wv, xb, wbig, wkb, wvb);

    // 2) fused QKV projection + RoPE + V-transpose (+ wo cast in tail if room)
    {
        dim3 g(8, fuse_wo ? 88 : 24, 1);
        gemm_qkv<<<g, 512, 0, stream>>>(xb, wbig, wkb, wvb, qb, kb, vtb, cosp, sinp,
                                        wo, fuse_wo ? wob : wbig);
    }

    // 3) flash attention (1 head/block, 2 blocks/CU, paired-causal q-tiles)
    {
        dim3 g(16, 32, 1);
        flash_attn<<<g, 256, 0, stream>>>(qb, kb, vtb, yb);
    }

    // 4) output projection (wo cast separately only if it didn't fit in ws)
    const ushort_t* wo_b = fuse_wo ? wob : wbig;
    if (!fuse_wo)
        cast_f32_bf16<<<16384, 256, 0, stream>>>(wo, wbig, 4096 * 4096 / 4);
    {
        dim3 g(8, 32, 1);
        gemm_bt<<<g, 512, 0, stream>>>(yb, wo_b, out, 2048, 4096, 4096);
    }
}